// Round 2
// baseline (2783.662 us; speedup 1.0000x reference)
//
#include <hip/hip_runtime.h>
#include <hip/hip_bf16.h>

#define Bq    4
#define NPTS  16384
#define SPTS  2048
#define D1c   128
#define D2c   256
#define FI    64
#define CIN1  384
#define M1c   256
#define M2c   128
#define CNTF  65536.0f
#define BNEPS 1e-5f

typedef unsigned short u16t;

__device__ __forceinline__ float b2f(u16t u){
  union { unsigned int i; float f; } v; v.i = ((unsigned int)u) << 16; return v.f;
}
__device__ __forceinline__ u16t f2b(float f){
  __hip_bfloat16 h = __float2bfloat16(f);
  return *reinterpret_cast<u16t*>(&h);
}
__device__ __forceinline__ float lrelu(float x){ return x >= 0.0f ? x : 0.2f*x; }
__device__ __forceinline__ float ldx(const u16t* p){ return b2f(*p); }
__device__ __forceinline__ float ldx(const float* p){ return *p; }

// ---- stats offsets (f32 elements): per-channel [sum, sumsq] pairs ----
#define ST_WG  0
#define ST_WX  128
#define ST_PSI 256
#define ST_BN1 272
#define ST_BN2 784

// ---- ws byte offsets ----
#define O_STATS  0u
#define O_IDX3   8192u
#define O_W3     (O_IDX3 + 786432u)
#define O_P2T    (O_W3 + 786432u)
#define O_INTERP (O_P2T + 4194304u)
#define O_YG     (O_INTERP + 33554432u)
#define O_YX     (O_YG + 8388608u)
#define O_PSIPRE (O_YX + 8388608u)
#define O_H1     (O_PSIPRE + 262144u)
// total ws = O_H1 + 33554432 = ~90 MB

// ---- 3-NN: per query point, 3 smallest squared distances (stable tie-break) ----
__global__ __launch_bounds__(256) void knn_kernel(const float* __restrict__ xyz1, const float* __restrict__ xyz2,
                                                  int* __restrict__ idx3, float* __restrict__ w3){
  __shared__ float sx[SPTS], sy[SPTS], sz[SPTS], ss[SPTS];
  const int b = blockIdx.y;
  for (int i = threadIdx.x; i < SPTS; i += 256){
    float x = xyz2[(b*3+0)*SPTS+i];
    float y = xyz2[(b*3+1)*SPTS+i];
    float z = xyz2[(b*3+2)*SPTS+i];
    sx[i]=x; sy[i]=y; sz[i]=z; ss[i]=x*x+y*y+z*z;
  }
  __syncthreads();
  const int n = blockIdx.x*256 + threadIdx.x;
  float px = xyz1[(b*3+0)*NPTS+n];
  float py = xyz1[(b*3+1)*NPTS+n];
  float pz = xyz1[(b*3+2)*NPTS+n];
  float s1 = px*px+py*py+pz*pz;
  float d0=3.4e38f, d1=3.4e38f, d2=3.4e38f;
  int   i0=0, i1=0, i2=0;
  for (int s=0; s<SPTS; ++s){
    float dot = fmaf(pz, sz[s], fmaf(py, sy[s], px*sx[s]));
    float key = (s1 + ss[s]) - 2.0f*dot;
    if (key < d2){
      if (key < d1){
        if (key < d0){ d2=d1; i2=i1; d1=d0; i1=i0; d0=key; i0=s; }
        else         { d2=d1; i2=i1; d1=key; i1=s; }
      } else         { d2=key; i2=s; }
    }
  }
  float r0=1.0f/(d0+1e-8f), r1=1.0f/(d1+1e-8f), r2=1.0f/(d2+1e-8f);
  float rs = r0+r1+r2;
  size_t base = ((size_t)b*NPTS + n)*3;
  idx3[base]=i0; idx3[base+1]=i1; idx3[base+2]=i2;
  w3[base]=r0/rs; w3[base+1]=r1/rs; w3[base+2]=r2/rs;
}

// ---- points2 [B][D2][S] f32 -> p2t [B][S][D2] bf16 ----
__global__ __launch_bounds__(256) void transpose_p2_kernel(const float* __restrict__ p2, u16t* __restrict__ p2t){
  int idx = blockIdx.x*256 + threadIdx.x;     // c fastest -> coalesced write
  int c = idx & (D2c-1);
  int s = (idx >> 8) & (SPTS-1);
  int b = idx >> 19;
  p2t[idx] = f2b(p2[((size_t)b*D2c + c)*SPTS + s]);
}

// ---- interp [B][D2][N] bf16 = sum_k w_k * p2t[idx_k] ----
__global__ __launch_bounds__(256) void interp_kernel(const u16t* __restrict__ p2t, const int* __restrict__ idx3,
                                                     const float* __restrict__ w3, u16t* __restrict__ interp){
  const int tile = blockIdx.x;
  const int b = tile >> 8;
  const int n0 = (tile & 255) * 64;
  const int wave = __builtin_amdgcn_readfirstlane((int)(threadIdx.x >> 6));
  const int lane = threadIdx.x & 63;
  const int n = n0 + lane;
  size_t pb = ((size_t)b*NPTS + n)*3;
  int i0 = idx3[pb], i1 = idx3[pb+1], i2 = idx3[pb+2];
  float w0 = w3[pb], w1 = w3[pb+1], w2 = w3[pb+2];
  const u16t* r0 = p2t + ((size_t)b*SPTS + i0)*D2c;
  const u16t* r1 = p2t + ((size_t)b*SPTS + i1)*D2c;
  const u16t* r2 = p2t + ((size_t)b*SPTS + i2)*D2c;
  for (int c = wave*64; c < wave*64 + 64; c += 8){
    uint4 q0 = *reinterpret_cast<const uint4*>(r0 + c);
    uint4 q1 = *reinterpret_cast<const uint4*>(r1 + c);
    uint4 q2 = *reinterpret_cast<const uint4*>(r2 + c);
    const unsigned int* a0 = reinterpret_cast<const unsigned int*>(&q0);
    const unsigned int* a1 = reinterpret_cast<const unsigned int*>(&q1);
    const unsigned int* a2 = reinterpret_cast<const unsigned int*>(&q2);
    #pragma unroll
    for (int j = 0; j < 4; ++j){
      unsigned int u0 = a0[j], u1 = a1[j], u2 = a2[j];
      float lo = fmaf(w2, b2f((u16t)u2), fmaf(w1, b2f((u16t)u1), w0*b2f((u16t)u0)));
      float hi = fmaf(w2, b2f((u16t)(u2>>16)), fmaf(w1, b2f((u16t)(u1>>16)), w0*b2f((u16t)(u0>>16))));
      interp[((size_t)b*D2c + c + 2*j    )*NPTS + n] = f2b(lo);
      interp[((size_t)b*D2c + c + 2*j + 1)*NPTS + n] = f2b(hi);
    }
  }
}

// ---- generic conv1x1 (raw bf16 output + batch stats), lane=point, scalar weights ----
template<typename T, int CIN, int OUT>
__global__ __launch_bounds__(256) void conv_raw_kernel(const T* __restrict__ x, const float* __restrict__ W,
                                                       const float* __restrict__ bias, u16t* __restrict__ y,
                                                       float* __restrict__ stats){
  constexpr int OPW = OUT/4;
  const int tile = blockIdx.x;
  const int b = tile >> 8;
  const int n0 = (tile & 255)*64;
  const int wave = __builtin_amdgcn_readfirstlane((int)(threadIdx.x >> 6));
  const int lane = threadIdx.x & 63;
  const int n = n0 + lane;
  float acc[OPW];
  #pragma unroll
  for (int f=0; f<OPW; ++f) acc[f]=0.f;
  const T* xb = x + (size_t)b*CIN*NPTS + n;
  const float* Wb = W + (size_t)wave*OPW*CIN;
  for (int c=0; c<CIN; ++c){
    float xv = ldx(xb + (size_t)c*NPTS);
    #pragma unroll
    for (int f=0; f<OPW; ++f)
      acc[f] = fmaf(Wb[f*CIN + c], xv, acc[f]);
  }
  #pragma unroll
  for (int f=0; f<OPW; ++f){
    int fo = wave*OPW + f;
    float v = acc[f] + bias[fo];
    y[((size_t)b*OUT + fo)*NPTS + n] = f2b(v);
    float s = v, q = v*v;
    #pragma unroll
    for (int o=32; o; o>>=1){ s += __shfl_xor(s, o); q += __shfl_xor(q, o); }
    if (lane == 0){ atomicAdd(&stats[fo*2], s); atomicAdd(&stats[fo*2+1], q); }
  }
}

// ---- gate: psi_pre = psi_w . lrelu(bn(yg)+bn(yx)) + psi_b, plus psi stats ----
__global__ __launch_bounds__(256) void gate_apply_kernel(const u16t* __restrict__ yg, const u16t* __restrict__ yx,
                                                         const float* __restrict__ stats_g, const float* __restrict__ stats_x,
                                                         const float* __restrict__ wg_bn_g, const float* __restrict__ wg_bn_b,
                                                         const float* __restrict__ wx_bn_g, const float* __restrict__ wx_bn_b,
                                                         const float* __restrict__ psi_w, const float* __restrict__ psi_b,
                                                         float* __restrict__ psi_pre, float* __restrict__ stats_psi){
  __shared__ float ag[FI], bg[FI], ax[FI], bx[FI], pw[FI];
  if (threadIdx.x < FI){
    int f = threadIdx.x;
    float m  = stats_g[f*2] * (1.0f/CNTF);
    float vv = fmaxf(stats_g[f*2+1]*(1.0f/CNTF) - m*m, 0.0f);
    float iv = 1.0f/sqrtf(vv + BNEPS);
    float gm = wg_bn_g[f];
    ag[f] = gm*iv; bg[f] = wg_bn_b[f] - m*gm*iv;
    m  = stats_x[f*2] * (1.0f/CNTF);
    vv = fmaxf(stats_x[f*2+1]*(1.0f/CNTF) - m*m, 0.0f);
    iv = 1.0f/sqrtf(vv + BNEPS);
    gm = wx_bn_g[f];
    ax[f] = gm*iv; bx[f] = wx_bn_b[f] - m*gm*iv;
    pw[f] = psi_w[f];
  }
  __syncthreads();
  const int p = blockIdx.x*256 + threadIdx.x;
  const int b = p >> 14;
  const int n = p & (NPTS-1);
  float acc = psi_b[0];
  for (int f=0; f<FI; ++f){
    float g  = fmaf(b2f(yg[((size_t)b*FI+f)*NPTS + n]), ag[f], bg[f]);
    float xv = fmaf(b2f(yx[((size_t)b*FI+f)*NPTS + n]), ax[f], bx[f]);
    acc = fmaf(pw[f], lrelu(g + xv), acc);
  }
  psi_pre[p] = acc;
  float s = acc, q = acc*acc;
  #pragma unroll
  for (int o=32; o; o>>=1){ s += __shfl_xor(s, o); q += __shfl_xor(q, o); }
  if ((threadIdx.x & 63) == 0){ atomicAdd(&stats_psi[0], s); atomicAdd(&stats_psi[1], q); }
}

// ---- conv1: x = [points1*psi ; interp] (384ch) -> h1 (256ch raw bf16) + stats ----
__global__ __launch_bounds__(256) void conv1_kernel(const float* __restrict__ points1, const u16t* __restrict__ interp,
                                                    const float* __restrict__ psi_pre, const float* __restrict__ stats_psi,
                                                    const float* __restrict__ psi_bn_g, const float* __restrict__ psi_bn_b,
                                                    const float* __restrict__ conv1_w, const float* __restrict__ conv1_b,
                                                    u16t* __restrict__ h1, float* __restrict__ stats1){
  const int tile = blockIdx.x;
  const int b = tile >> 8;
  const int n0 = (tile & 255)*64;
  const int wave = __builtin_amdgcn_readfirstlane((int)(threadIdx.x >> 6));
  const int lane = threadIdx.x & 63;
  const int n = n0 + lane;
  float m  = stats_psi[0]*(1.0f/CNTF);
  float vv = fmaxf(stats_psi[1]*(1.0f/CNTF) - m*m, 0.0f);
  float iv = 1.0f/sqrtf(vv + BNEPS);
  float ap = psi_bn_g[0]*iv;
  float bp = psi_bn_b[0] - m*ap;
  float z  = fmaf(psi_pre[b*NPTS + n], ap, bp);
  float psi = 1.0f/(1.0f + expf(-z));
  float acc[64];
  #pragma unroll
  for (int f=0; f<64; ++f) acc[f]=0.f;
  const float* Wb = conv1_w + (size_t)wave*64*CIN1;
  const float* xp = points1 + (size_t)b*D1c*NPTS + n;
  for (int c=0; c<D1c; ++c){
    float xv = xp[(size_t)c*NPTS] * psi;
    #pragma unroll
    for (int f=0; f<64; ++f) acc[f] = fmaf(Wb[f*CIN1 + c], xv, acc[f]);
  }
  const u16t* xi = interp + (size_t)b*D2c*NPTS + n;
  for (int c=0; c<D2c; ++c){
    float xv = b2f(xi[(size_t)c*NPTS]);
    #pragma unroll
    for (int f=0; f<64; ++f) acc[f] = fmaf(Wb[f*CIN1 + D1c + c], xv, acc[f]);
  }
  #pragma unroll
  for (int f=0; f<64; ++f){
    int fo = wave*64 + f;
    float v = acc[f] + conv1_b[fo];
    h1[((size_t)b*M1c + fo)*NPTS + n] = f2b(v);
    float s = v, q = v*v;
    #pragma unroll
    for (int o=32; o; o>>=1){ s += __shfl_xor(s, o); q += __shfl_xor(q, o); }
    if (lane == 0){ atomicAdd(&stats1[fo*2], s); atomicAdd(&stats1[fo*2+1], q); }
  }
}

// ---- conv2: x = lrelu(bn1(h1)) (256ch) -> raw f32 into d_out + stats ----
__global__ __launch_bounds__(256) void conv2_kernel(const u16t* __restrict__ h1, const float* __restrict__ stats1,
                                                    const float* __restrict__ bn1_g, const float* __restrict__ bn1_b,
                                                    const float* __restrict__ conv2_w, const float* __restrict__ conv2_b,
                                                    float* __restrict__ h2, float* __restrict__ stats2){
  __shared__ float a1[M1c], c1[M1c];
  {
    int c = threadIdx.x;
    float m  = stats1[c*2]*(1.0f/CNTF);
    float vv = fmaxf(stats1[c*2+1]*(1.0f/CNTF) - m*m, 0.0f);
    float iv = 1.0f/sqrtf(vv + BNEPS);
    float gm = bn1_g[c];
    a1[c] = gm*iv; c1[c] = bn1_b[c] - m*gm*iv;
  }
  __syncthreads();
  const int tile = blockIdx.x;
  const int b = tile >> 8;
  const int n0 = (tile & 255)*64;
  const int wave = __builtin_amdgcn_readfirstlane((int)(threadIdx.x >> 6));
  const int lane = threadIdx.x & 63;
  const int n = n0 + lane;
  float acc[32];
  #pragma unroll
  for (int f=0; f<32; ++f) acc[f]=0.f;
  const float* Wb = conv2_w + (size_t)wave*32*M1c;
  const u16t* xb = h1 + (size_t)b*M1c*NPTS + n;
  for (int c=0; c<M1c; ++c){
    float v = fmaf(b2f(xb[(size_t)c*NPTS]), a1[c], c1[c]);
    v = lrelu(v);
    #pragma unroll
    for (int f=0; f<32; ++f) acc[f] = fmaf(Wb[f*M1c + c], v, acc[f]);
  }
  #pragma unroll
  for (int f=0; f<32; ++f){
    int fo = wave*32 + f;
    float v = acc[f] + conv2_b[fo];
    h2[((size_t)b*M2c + fo)*NPTS + n] = v;
    float s = v, q = v*v;
    #pragma unroll
    for (int o=32; o; o>>=1){ s += __shfl_xor(s, o); q += __shfl_xor(q, o); }
    if (lane == 0){ atomicAdd(&stats2[fo*2], s); atomicAdd(&stats2[fo*2+1], q); }
  }
}

// ---- out = lrelu(bn2(h2)) in place on d_out (f32) ----
__global__ __launch_bounds__(256) void final_kernel(float* __restrict__ h2, const float* __restrict__ stats2,
                                                    const float* __restrict__ bn2_g, const float* __restrict__ bn2_b){
  int idx = blockIdx.x*256 + threadIdx.x;    // [b][f][n], n fastest
  int f = (idx >> 14) & (M2c-1);
  float m  = stats2[f*2]*(1.0f/CNTF);
  float vv = fmaxf(stats2[f*2+1]*(1.0f/CNTF) - m*m, 0.0f);
  float iv = 1.0f/sqrtf(vv + BNEPS);
  float a  = bn2_g[f]*iv;
  float c  = bn2_b[f] - m*a;
  float v  = fmaf(h2[idx], a, c);
  h2[idx] = lrelu(v);
}

extern "C" void kernel_launch(void* const* d_in, const int* in_sizes, int n_in,
                              void* d_out, int out_size, void* d_ws, size_t ws_size,
                              hipStream_t stream){
  const float* xyz1    = (const float*)d_in[0];
  const float* xyz2    = (const float*)d_in[1];
  const float* points1 = (const float*)d_in[2];
  const float* points2 = (const float*)d_in[3];
  const float* conv1_w = (const float*)d_in[4];
  const float* conv1_b = (const float*)d_in[5];
  const float* bn1_g   = (const float*)d_in[6];
  const float* bn1_b   = (const float*)d_in[7];
  const float* conv2_w = (const float*)d_in[8];
  const float* conv2_b = (const float*)d_in[9];
  const float* bn2_g   = (const float*)d_in[10];
  const float* bn2_b   = (const float*)d_in[11];
  const float* wg_w    = (const float*)d_in[12];
  const float* wg_b    = (const float*)d_in[13];
  const float* wg_bn_g = (const float*)d_in[14];
  const float* wg_bn_b = (const float*)d_in[15];
  const float* wx_w    = (const float*)d_in[16];
  const float* wx_b    = (const float*)d_in[17];
  const float* wx_bn_g = (const float*)d_in[18];
  const float* wx_bn_b = (const float*)d_in[19];
  const float* psi_w   = (const float*)d_in[20];
  const float* psi_b   = (const float*)d_in[21];
  const float* psi_bn_g= (const float*)d_in[22];
  const float* psi_bn_b= (const float*)d_in[23];

  char* ws = (char*)d_ws;
  float* stats  = (float*)(ws + O_STATS);
  int*   idx3   = (int*)(ws + O_IDX3);
  float* w3     = (float*)(ws + O_W3);
  u16t*  p2t    = (u16t*)(ws + O_P2T);
  u16t*  interp = (u16t*)(ws + O_INTERP);
  u16t*  yg     = (u16t*)(ws + O_YG);
  u16t*  yx     = (u16t*)(ws + O_YX);
  float* psipre = (float*)(ws + O_PSIPRE);
  u16t*  h1     = (u16t*)(ws + O_H1);
  float* h2     = (float*)d_out;

  hipMemsetAsync(ws + O_STATS, 0, 8192, stream);

  knn_kernel<<<dim3(NPTS/256, Bq), 256, 0, stream>>>(xyz1, xyz2, idx3, w3);
  transpose_p2_kernel<<<(Bq*SPTS*D2c)/256, 256, 0, stream>>>(points2, p2t);
  interp_kernel<<<Bq*(NPTS/64), 256, 0, stream>>>(p2t, idx3, w3, interp);

  conv_raw_kernel<u16t,  D2c, FI><<<Bq*(NPTS/64), 256, 0, stream>>>(interp,  wg_w, wg_b, yg, stats+ST_WG);
  conv_raw_kernel<float, D1c, FI><<<Bq*(NPTS/64), 256, 0, stream>>>(points1, wx_w, wx_b, yx, stats+ST_WX);
  gate_apply_kernel<<<(Bq*NPTS)/256, 256, 0, stream>>>(yg, yx, stats+ST_WG, stats+ST_WX,
                                                       wg_bn_g, wg_bn_b, wx_bn_g, wx_bn_b,
                                                       psi_w, psi_b, psipre, stats+ST_PSI);

  conv1_kernel<<<Bq*(NPTS/64), 256, 0, stream>>>(points1, interp, psipre, stats+ST_PSI,
                                                 psi_bn_g, psi_bn_b, conv1_w, conv1_b, h1, stats+ST_BN1);
  conv2_kernel<<<Bq*(NPTS/64), 256, 0, stream>>>(h1, stats+ST_BN1, bn1_g, bn1_b, conv2_w, conv2_b, h2, stats+ST_BN2);
  final_kernel<<<(Bq*M2c*NPTS)/256, 256, 0, stream>>>(h2, stats+ST_BN2, bn2_g, bn2_b);
}

// Round 4
// 619.154 us; speedup vs baseline: 4.4959x; 4.4959x over previous
//
#include <hip/hip_runtime.h>
#include <hip/hip_bf16.h>

#define Bq    4
#define NPTS  16384
#define SPTS  2048
#define CNTF  65536.0f
#define BNEPS 1e-5f

typedef unsigned short u16t;
typedef unsigned int   u32t;
typedef __attribute__((ext_vector_type(8))) short s16x8;
typedef __attribute__((ext_vector_type(4))) float f32x4;

__device__ __forceinline__ float b2f(u16t u){
  union { u32t i; float f; } v; v.i = ((u32t)u) << 16; return v.f;
}
__device__ __forceinline__ u16t f2b(float f){
  __hip_bfloat16 h = __float2bfloat16(f);
  return *reinterpret_cast<u16t*>(&h);
}
__device__ __forceinline__ float lrelu(float x){ return x >= 0.0f ? x : 0.2f*x; }
__device__ __forceinline__ float ldx(const u16t* p){ return b2f(*p); }
__device__ __forceinline__ float ldx(const float* p){ return *p; }

// ---- stats f32 offsets: per-channel [sum,sumsq] pairs ----
#define ST_WG  0
#define ST_WX  128
#define ST_PSI 256
#define ST_BN1 272
#define ST_BN2 784

// ---- bf16 weight element offsets inside WB region ----
#define WOFF_C1 0
#define WOFF_C2 98304
#define WOFF_WG 131072
#define WOFF_WX 147456
#define WTOTAL  155648

// ---- ws byte offsets (time-disjoint aliasing; total ~84.6 MB) ----
#define O_STATS  0u
#define O_WB     8192u
#define O_PSIPRE 319488u
#define O_P2T    581632u        // 4 MB bf16 [B][S][256]
#define O_P1T    4775936u       // 16.7 MB bf16 [B][N][128]; psi-scaled IN PLACE
#define O_INT    21553152u      // 33.5 MB bf16 [B][N][256] interp; h2t aliases later
#define O_H1     55107584u      // 33.5 MB bf16 [B][N][256] h1; bnrelu IN PLACE
#define O_IDX3   O_H1                    // idx3 lives steps 1-3, dead before ygt written
#define O_W3     (O_H1 + 786432u)
#define O_YG     O_H1                    // ygt/yxt live steps 5-8, dead before h1 written
#define O_YX     (O_H1 + 8388608u)
#define O_H2     O_INT                   // h2 bf16, written after interp dead
// end = 55107584 + 33554432 = 88662016 B

// ---- 3-NN (unchanged, passing) ----
__global__ __launch_bounds__(256) void knn_kernel(const float* __restrict__ xyz1, const float* __restrict__ xyz2,
                                                  int* __restrict__ idx3, float* __restrict__ w3){
  __shared__ float sx[SPTS], sy[SPTS], sz[SPTS], ss[SPTS];
  const int b = blockIdx.y;
  for (int i = threadIdx.x; i < SPTS; i += 256){
    float x = xyz2[(b*3+0)*SPTS+i];
    float y = xyz2[(b*3+1)*SPTS+i];
    float z = xyz2[(b*3+2)*SPTS+i];
    sx[i]=x; sy[i]=y; sz[i]=z; ss[i]=x*x+y*y+z*z;
  }
  __syncthreads();
  const int n = blockIdx.x*256 + threadIdx.x;
  float px = xyz1[(b*3+0)*NPTS+n];
  float py = xyz1[(b*3+1)*NPTS+n];
  float pz = xyz1[(b*3+2)*NPTS+n];
  float s1 = px*px+py*py+pz*pz;
  float d0=3.4e38f, d1=3.4e38f, d2=3.4e38f;
  int   i0=0, i1=0, i2=0;
  for (int s=0; s<SPTS; ++s){
    float dot = fmaf(pz, sz[s], fmaf(py, sy[s], px*sx[s]));
    float key = (s1 + ss[s]) - 2.0f*dot;
    if (key < d2){
      if (key < d1){
        if (key < d0){ d2=d1; i2=i1; d1=d0; i1=i0; d0=key; i0=s; }
        else         { d2=d1; i2=i1; d1=key; i1=s; }
      } else         { d2=key; i2=s; }
    }
  }
  float r0=1.0f/(d0+1e-8f), r1=1.0f/(d1+1e-8f), r2=1.0f/(d2+1e-8f);
  float rs = r0+r1+r2;
  size_t base = ((size_t)b*NPTS + n)*3;
  idx3[base]=i0; idx3[base+1]=i1; idx3[base+2]=i2;
  w3[base]=r0/rs; w3[base+1]=r1/rs; w3[base+2]=r2/rs;
}

// ---- tiled transpose: src f32 [B][C][NN] -> dst bf16 [B][NN][C] ----
template<int C, int NN>
__global__ __launch_bounds__(256) void tpose_kernel(const float* __restrict__ src, u16t* __restrict__ dst){
  __shared__ float tile[64][65];
  const int n0 = blockIdx.x * 64;
  const int c0 = blockIdx.y * 64;
  const int b  = blockIdx.z;
  const int t  = threadIdx.x;
  #pragma unroll
  for (int i = 0; i < 16; ++i){
    int idx = t + i*256;
    int cc = idx >> 6, nn = idx & 63;
    tile[cc][nn] = src[((size_t)b*C + c0 + cc)*NN + n0 + nn];
  }
  __syncthreads();
  #pragma unroll
  for (int i = 0; i < 16; ++i){
    int idx = t + i*256;
    int nn = idx >> 6, cc = idx & 63;
    dst[((size_t)b*NN + n0 + nn)*C + c0 + cc] = f2b(tile[cc][nn]);
  }
}

// ---- weight convert f32 -> bf16 into WB ----
__global__ __launch_bounds__(256) void wcvt_kernel(const float* __restrict__ w1, const float* __restrict__ w2,
                                                   const float* __restrict__ wg, const float* __restrict__ wx,
                                                   u16t* __restrict__ wb){
  int i = blockIdx.x*256 + threadIdx.x;
  if (i >= WTOTAL) return;
  float v;
  if      (i < WOFF_C2) v = w1[i];
  else if (i < WOFF_WG) v = w2[i - WOFF_C2];
  else if (i < WOFF_WX) v = wg[i - WOFF_WG];
  else                  v = wx[i - WOFF_WX];
  wb[i] = f2b(v);
}

// ---- interp: point-major out [B][N][256] ----
__global__ __launch_bounds__(256) void interp_kernel(const u16t* __restrict__ p2t, const int* __restrict__ idx3,
                                                     const float* __restrict__ w3, u16t* __restrict__ it){
  const int bid = blockIdx.x;
  const int b = bid >> 8;
  const int n0 = (bid & 255) * 64;
  const int wv = threadIdx.x >> 6;
  const int lane = threadIdx.x & 63;
  const int n = n0 + lane;
  size_t pb = ((size_t)b*NPTS + n)*3;
  int i0 = idx3[pb], i1 = idx3[pb+1], i2 = idx3[pb+2];
  float w0 = w3[pb], w1 = w3[pb+1], w2 = w3[pb+2];
  const u16t* r0 = p2t + ((size_t)b*SPTS + i0)*256;
  const u16t* r1 = p2t + ((size_t)b*SPTS + i1)*256;
  const u16t* r2 = p2t + ((size_t)b*SPTS + i2)*256;
  u16t* orow = it + ((size_t)b*NPTS + n)*256;
  for (int c = wv*64; c < wv*64 + 64; c += 8){
    uint4 q0 = *reinterpret_cast<const uint4*>(r0 + c);
    uint4 q1 = *reinterpret_cast<const uint4*>(r1 + c);
    uint4 q2 = *reinterpret_cast<const uint4*>(r2 + c);
    const u32t* a0 = reinterpret_cast<const u32t*>(&q0);
    const u32t* a1 = reinterpret_cast<const u32t*>(&q1);
    const u32t* a2 = reinterpret_cast<const u32t*>(&q2);
    u32t ow[4];
    #pragma unroll
    for (int j = 0; j < 4; ++j){
      u32t u0 = a0[j], u1 = a1[j], u2 = a2[j];
      float lo = fmaf(w2, b2f((u16t)u2), fmaf(w1, b2f((u16t)u1), w0*b2f((u16t)u0)));
      float hi = fmaf(w2, b2f((u16t)(u2>>16)), fmaf(w1, b2f((u16t)(u1>>16)), w0*b2f((u16t)(u0>>16))));
      ow[j] = (u32t)f2b(lo) | ((u32t)f2b(hi) << 16);
    }
    *reinterpret_cast<uint4*>(orow + c) = make_uint4(ow[0], ow[1], ow[2], ow[3]);
  }
}

// ---- MFMA conv1x1: y[B][N][OUT] = W[OUT][CIN] . x[B][N][CIN] + bias (raw, pre-BN) ----
template<int CIN, int OUT, bool SPLIT>
__global__ __launch_bounds__(256, 1) void mfma_conv_kernel(const u16t* __restrict__ xa, const u16t* __restrict__ xb,
                                                           const u16t* __restrict__ W, const float* __restrict__ bias,
                                                           u16t* __restrict__ y){
  constexpr int MW = OUT/4;      // per-wave M slice
  constexpr int MF = MW/16;      // m-fragments per wave
  constexpr int KS = CIN/32;     // k-steps
  const int bid = blockIdx.x;
  const int b = bid >> 8;
  const int n0 = (bid & 255) * 64;
  const int wv = threadIdx.x >> 6;
  const int lane = threadIdx.x & 63;
  const int lr = lane & 15;
  const int kg = lane >> 4;
  const int m0 = wv * MW;

  f32x4 acc[MF][4];
  #pragma unroll
  for (int mf = 0; mf < MF; ++mf)
    #pragma unroll
    for (int nf = 0; nf < 4; ++nf){ acc[mf][nf][0]=0.f; acc[mf][nf][1]=0.f; acc[mf][nf][2]=0.f; acc[mf][nf][3]=0.f; }

  const u16t* bA[4]; const u16t* bB[4];
  #pragma unroll
  for (int nf = 0; nf < 4; ++nf){
    int n = n0 + nf*16 + lr;
    if (SPLIT){
      bA[nf] = xa + ((size_t)b*NPTS + n)*128 + kg*8;
      bB[nf] = xb + ((size_t)b*NPTS + n)*256 + kg*8;
    } else {
      bA[nf] = xa + ((size_t)b*NPTS + n)*CIN + kg*8;
    }
  }

  #pragma unroll
  for (int k0 = 0; k0 < KS; ++k0){
    s16x8 av[MF];
    #pragma unroll
    for (int mf = 0; mf < MF; ++mf)
      av[mf] = *reinterpret_cast<const s16x8*>(W + (size_t)(m0 + mf*16 + lr)*CIN + k0*32 + kg*8);
    s16x8 bv[4];
    #pragma unroll
    for (int nf = 0; nf < 4; ++nf){
      const u16t* p;
      if (SPLIT) p = (k0 < 4) ? (bA[nf] + k0*32) : (bB[nf] + (k0-4)*32);
      else       p = bA[nf] + k0*32;
      bv[nf] = *reinterpret_cast<const s16x8*>(p);
    }
    #pragma unroll
    for (int mf = 0; mf < MF; ++mf)
      #pragma unroll
      for (int nf = 0; nf < 4; ++nf)
        acc[mf][nf] = __builtin_amdgcn_mfma_f32_16x16x32_bf16(av[mf], bv[nf], acc[mf][nf], 0, 0, 0);
  }

  #pragma unroll
  for (int mf = 0; mf < MF; ++mf){
    int mb = m0 + mf*16 + kg*4;
    float4 bs = *reinterpret_cast<const float4*>(bias + mb);
    #pragma unroll
    for (int nf = 0; nf < 4; ++nf){
      int n = n0 + nf*16 + lr;
      float v0 = acc[mf][nf][0] + bs.x;
      float v1 = acc[mf][nf][1] + bs.y;
      float v2 = acc[mf][nf][2] + bs.z;
      float v3 = acc[mf][nf][3] + bs.w;
      uint2 pv;
      pv.x = (u32t)f2b(v0) | ((u32t)f2b(v1) << 16);
      pv.y = (u32t)f2b(v2) | ((u32t)f2b(v3) << 16);
      *reinterpret_cast<uint2*>(y + ((size_t)b*NPTS + n)*OUT + mb) = pv;
    }
  }
}

// ---- batch stats: sum/sumsq per channel over all B*N points; x is [P][C] ----
template<int C, typename T>
__global__ __launch_bounds__(256) void stats_kernel(const T* __restrict__ x, float* __restrict__ st){
  constexpr int G = 256 / C;
  const int t = threadIdx.x;
  const int c = t & (C - 1);
  const int g = t / C;
  const int p0 = blockIdx.x * 256;
  float s = 0.f, q = 0.f;
  for (int i = g; i < 256; i += G){
    float v = ldx(x + (size_t)(p0 + i)*C + c);
    s += v; q += v*v;
  }
  if (G > 1){
    __shared__ float ls[256], lq[256];
    ls[t] = s; lq[t] = q;
    __syncthreads();
    if (t < C){
      #pragma unroll
      for (int gg = 1; gg < G; ++gg){ s += ls[t + gg*C]; q += lq[t + gg*C]; }
      atomicAdd(&st[c*2], s); atomicAdd(&st[c*2+1], q);
    }
  } else {
    atomicAdd(&st[c*2], s); atomicAdd(&st[c*2+1], q);
  }
}

// ---- gate: psi_pre[p] = psi_w . lrelu(bn(yg)+bn(yx)) + psi_b, + psi stats ----
__global__ __launch_bounds__(256) void gate_kernel(const u16t* __restrict__ yg, const u16t* __restrict__ yx,
                                                   const float* __restrict__ stg, const float* __restrict__ stx,
                                                   const float* __restrict__ wg_bn_g, const float* __restrict__ wg_bn_b,
                                                   const float* __restrict__ wx_bn_g, const float* __restrict__ wx_bn_b,
                                                   const float* __restrict__ psi_w, const float* __restrict__ psi_b,
                                                   float* __restrict__ psipre, float* __restrict__ stpsi){
  __shared__ float lag[64], lbg[64], lax[64], lbx[64], lpw[64];
  __shared__ float red[8];
  const int t = threadIdx.x;
  if (t < 64){
    float m  = stg[t*2] * (1.0f/CNTF);
    float vv = fmaxf(stg[t*2+1]*(1.0f/CNTF) - m*m, 0.0f);
    float iv = 1.0f/sqrtf(vv + BNEPS);
    float gm = wg_bn_g[t];
    lag[t] = gm*iv; lbg[t] = wg_bn_b[t] - m*gm*iv;
    m  = stx[t*2] * (1.0f/CNTF);
    vv = fmaxf(stx[t*2+1]*(1.0f/CNTF) - m*m, 0.0f);
    iv = 1.0f/sqrtf(vv + BNEPS);
    gm = wx_bn_g[t];
    lax[t] = gm*iv; lbx[t] = wx_bn_b[t] - m*gm*iv;
    lpw[t] = psi_w[t];
  }
  __syncthreads();
  const int p = blockIdx.x*256 + t;
  const u16t* rg = yg + (size_t)p*64;
  const u16t* rx = yx + (size_t)p*64;
  float acc = psi_b[0];
  #pragma unroll
  for (int u = 0; u < 8; ++u){   // FIX: 8 uint4 x 8 bf16 = all 64 channels (was 4 -> half dropped)
    uint4 qg = *reinterpret_cast<const uint4*>(rg + u*8);
    uint4 qx = *reinterpret_cast<const uint4*>(rx + u*8);
    const u32t* g4 = reinterpret_cast<const u32t*>(&qg);
    const u32t* x4 = reinterpret_cast<const u32t*>(&qx);
    #pragma unroll
    for (int e = 0; e < 4; ++e){
      int j = u*8 + e*2;
      float gv0 = fmaf(b2f((u16t)g4[e]),        lag[j],   lbg[j]);
      float xv0 = fmaf(b2f((u16t)x4[e]),        lax[j],   lbx[j]);
      float gv1 = fmaf(b2f((u16t)(g4[e]>>16)),  lag[j+1], lbg[j+1]);
      float xv1 = fmaf(b2f((u16t)(x4[e]>>16)),  lax[j+1], lbx[j+1]);
      acc = fmaf(lpw[j],   lrelu(gv0 + xv0), acc);
      acc = fmaf(lpw[j+1], lrelu(gv1 + xv1), acc);
    }
  }
  psipre[p] = acc;
  float s = acc, q = acc*acc;
  #pragma unroll
  for (int o = 32; o; o >>= 1){ s += __shfl_xor(s, o); q += __shfl_xor(q, o); }
  if ((t & 63) == 0){ red[(t>>6)*2] = s; red[(t>>6)*2+1] = q; }
  __syncthreads();
  if (t == 0){
    atomicAdd(&stpsi[0], red[0]+red[2]+red[4]+red[6]);
    atomicAdd(&stpsi[1], red[1]+red[3]+red[5]+red[7]);
  }
}

// ---- psi = sigmoid(bn(psi_pre)); scale p1t rows in place ----
__global__ __launch_bounds__(256) void scale_p1_kernel(u16t* __restrict__ p1t, const float* __restrict__ psipre,
                                                       const float* __restrict__ stpsi,
                                                       const float* __restrict__ psi_bn_g, const float* __restrict__ psi_bn_b){
  const int p = blockIdx.x*256 + threadIdx.x;
  float m  = stpsi[0]*(1.0f/CNTF);
  float vv = fmaxf(stpsi[1]*(1.0f/CNTF) - m*m, 0.0f);
  float iv = 1.0f/sqrtf(vv + BNEPS);
  float ap = psi_bn_g[0]*iv;
  float bp = psi_bn_b[0] - m*ap;
  float z  = fmaf(psipre[p], ap, bp);
  float psi = 1.0f/(1.0f + expf(-z));
  u16t* r = p1t + (size_t)p*128;
  #pragma unroll
  for (int u = 0; u < 16; ++u){
    uint4 q = *reinterpret_cast<uint4*>(r + u*8);
    u32t* a = reinterpret_cast<u32t*>(&q);
    #pragma unroll
    for (int j = 0; j < 4; ++j){
      float lo = b2f((u16t)a[j]) * psi;
      float hi = b2f((u16t)(a[j]>>16)) * psi;
      a[j] = (u32t)f2b(lo) | ((u32t)f2b(hi) << 16);
    }
    *reinterpret_cast<uint4*>(r + u*8) = q;
  }
}

// ---- bn1 + lrelu in place on h1 [P][256] bf16 ----
__global__ __launch_bounds__(256) void bnrelu256_kernel(u16t* __restrict__ x, const float* __restrict__ st,
                                                        const float* __restrict__ g, const float* __restrict__ bb){
  __shared__ float sa[256], sc[256];
  const int t = threadIdx.x;
  {
    float m  = st[t*2]*(1.0f/CNTF);
    float vv = fmaxf(st[t*2+1]*(1.0f/CNTF) - m*m, 0.0f);
    float iv = 1.0f/sqrtf(vv + BNEPS);
    float gm = g[t];
    sa[t] = gm*iv; sc[t] = bb[t] - m*gm*iv;
  }
  __syncthreads();
  size_t e4 = ((size_t)blockIdx.x*256 + t)*4;
  int c0 = (int)(e4 & 255);
  uint2 v = *reinterpret_cast<uint2*>(x + e4);
  float f0 = lrelu(fmaf(b2f((u16t)v.x),        sa[c0],   sc[c0]));
  float f1 = lrelu(fmaf(b2f((u16t)(v.x>>16)),  sa[c0+1], sc[c0+1]));
  float f2 = lrelu(fmaf(b2f((u16t)v.y),        sa[c0+2], sc[c0+2]));
  float f3 = lrelu(fmaf(b2f((u16t)(v.y>>16)),  sa[c0+3], sc[c0+3]));
  v.x = (u32t)f2b(f0) | ((u32t)f2b(f1) << 16);
  v.y = (u32t)f2b(f2) | ((u32t)f2b(f3) << 16);
  *reinterpret_cast<uint2*>(x + e4) = v;
}

// ---- final: out[b][m][n] f32 = lrelu(bn2(h2[b][n][m])) via LDS tile transpose ----
__global__ __launch_bounds__(256) void final_kernel(const u16t* __restrict__ h2, const float* __restrict__ st,
                                                    const float* __restrict__ g, const float* __restrict__ bb,
                                                    float* __restrict__ out){
  __shared__ float am[128], cm[128];
  __shared__ float tile[64][129];
  const int t = threadIdx.x;
  if (t < 128){
    float m  = st[t*2]*(1.0f/CNTF);
    float vv = fmaxf(st[t*2+1]*(1.0f/CNTF) - m*m, 0.0f);
    float iv = 1.0f/sqrtf(vv + BNEPS);
    float gm = g[t];
    am[t] = gm*iv; cm[t] = bb[t] - m*gm*iv;
  }
  __syncthreads();
  const int n0 = blockIdx.x * 64;
  const int b  = blockIdx.y;
  #pragma unroll
  for (int i = 0; i < 32; ++i){
    int idx = t + i*256;
    int mm = idx & 127, nn = idx >> 7;
    float v = fmaf(b2f(h2[((size_t)b*NPTS + n0 + nn)*128 + mm]), am[mm], cm[mm]);
    tile[nn][mm] = lrelu(v);
  }
  __syncthreads();
  #pragma unroll
  for (int i = 0; i < 32; ++i){
    int idx = t + i*256;
    int nn = idx & 63, mm = idx >> 6;
    out[((size_t)(b*128 + mm))*NPTS + n0 + nn] = tile[nn][mm];
  }
}

extern "C" void kernel_launch(void* const* d_in, const int* in_sizes, int n_in,
                              void* d_out, int out_size, void* d_ws, size_t ws_size,
                              hipStream_t stream){
  const float* xyz1    = (const float*)d_in[0];
  const float* xyz2    = (const float*)d_in[1];
  const float* points1 = (const float*)d_in[2];
  const float* points2 = (const float*)d_in[3];
  const float* conv1_w = (const float*)d_in[4];
  const float* conv1_b = (const float*)d_in[5];
  const float* bn1_g   = (const float*)d_in[6];
  const float* bn1_b   = (const float*)d_in[7];
  const float* conv2_w = (const float*)d_in[8];
  const float* conv2_b = (const float*)d_in[9];
  const float* bn2_g   = (const float*)d_in[10];
  const float* bn2_b   = (const float*)d_in[11];
  const float* wg_w    = (const float*)d_in[12];
  const float* wg_b    = (const float*)d_in[13];
  const float* wg_bn_g = (const float*)d_in[14];
  const float* wg_bn_b = (const float*)d_in[15];
  const float* wx_w    = (const float*)d_in[16];
  const float* wx_b    = (const float*)d_in[17];
  const float* wx_bn_g = (const float*)d_in[18];
  const float* wx_bn_b = (const float*)d_in[19];
  const float* psi_w   = (const float*)d_in[20];
  const float* psi_b   = (const float*)d_in[21];
  const float* psi_bn_g= (const float*)d_in[22];
  const float* psi_bn_b= (const float*)d_in[23];

  char* ws = (char*)d_ws;
  float* stats  = (float*)(ws + O_STATS);
  u16t*  wb     = (u16t*)(ws + O_WB);
  float* psipre = (float*)(ws + O_PSIPRE);
  u16t*  p2t    = (u16t*)(ws + O_P2T);
  u16t*  p1t    = (u16t*)(ws + O_P1T);
  u16t*  itp    = (u16t*)(ws + O_INT);
  u16t*  h1t    = (u16t*)(ws + O_H1);
  int*   idx3   = (int*)(ws + O_IDX3);
  float* w3     = (float*)(ws + O_W3);
  u16t*  ygt    = (u16t*)(ws + O_YG);
  u16t*  yxt    = (u16t*)(ws + O_YX);
  u16t*  h2t    = (u16t*)(ws + O_H2);

  hipMemsetAsync(ws + O_STATS, 0, 8192, stream);

  knn_kernel<<<dim3(NPTS/256, Bq), 256, 0, stream>>>(xyz1, xyz2, idx3, w3);
  tpose_kernel<256, SPTS><<<dim3(SPTS/64, 4, Bq), 256, 0, stream>>>(points2, p2t);
  interp_kernel<<<Bq*(NPTS/64), 256, 0, stream>>>(p2t, idx3, w3, itp);
  tpose_kernel<128, NPTS><<<dim3(NPTS/64, 2, Bq), 256, 0, stream>>>(points1, p1t);
  wcvt_kernel<<<(WTOTAL+255)/256, 256, 0, stream>>>(conv1_w, conv2_w, wg_w, wx_w, wb);

  mfma_conv_kernel<256, 64, false><<<Bq*(NPTS/64), 256, 0, stream>>>(itp, nullptr, wb+WOFF_WG, wg_b, ygt);
  mfma_conv_kernel<128, 64, false><<<Bq*(NPTS/64), 256, 0, stream>>>(p1t, nullptr, wb+WOFF_WX, wx_b, yxt);
  stats_kernel<64, u16t><<<256, 256, 0, stream>>>(ygt, stats+ST_WG);
  stats_kernel<64, u16t><<<256, 256, 0, stream>>>(yxt, stats+ST_WX);
  gate_kernel<<<256, 256, 0, stream>>>(ygt, yxt, stats+ST_WG, stats+ST_WX,
                                       wg_bn_g, wg_bn_b, wx_bn_g, wx_bn_b,
                                       psi_w, psi_b, psipre, stats+ST_PSI);
  scale_p1_kernel<<<256, 256, 0, stream>>>(p1t, psipre, stats+ST_PSI, psi_bn_g, psi_bn_b);

  mfma_conv_kernel<384, 256, true><<<Bq*(NPTS/64), 256, 0, stream>>>(p1t, itp, wb+WOFF_C1, conv1_b, h1t);
  stats_kernel<256, u16t><<<256, 256, 0, stream>>>(h1t, stats+ST_BN1);
  bnrelu256_kernel<<<16384, 256, 0, stream>>>(h1t, stats+ST_BN1, bn1_g, bn1_b);

  mfma_conv_kernel<256, 128, false><<<Bq*(NPTS/64), 256, 0, stream>>>(h1t, nullptr, wb+WOFF_C2, conv2_b, h2t);
  stats_kernel<128, u16t><<<256, 256, 0, stream>>>(h2t, stats+ST_BN2);
  final_kernel<<<dim3(NPTS/64, Bq), 256, 0, stream>>>(h2t, stats+ST_BN2, bn2_g, bn2_b, (float*)d_out);
}

// Round 5
// 471.897 us; speedup vs baseline: 5.8989x; 1.3121x over previous
//
#include <hip/hip_runtime.h>
#include <hip/hip_bf16.h>

#define Bq    4
#define NPTS  16384
#define SPTS  2048
#define NCH   8
#define SCH   (SPTS/NCH)   // 256
#define CNTF  65536.0f
#define BNEPS 1e-5f

typedef unsigned short u16t;
typedef unsigned int   u32t;
typedef __attribute__((ext_vector_type(8))) short s16x8;
typedef __attribute__((ext_vector_type(4))) float f32x4;

__device__ __forceinline__ float b2f(u16t u){
  union { u32t i; float f; } v; v.i = ((u32t)u) << 16; return v.f;
}
__device__ __forceinline__ u16t f2b(float f){
  __hip_bfloat16 h = __float2bfloat16(f);
  return *reinterpret_cast<u16t*>(&h);
}
__device__ __forceinline__ float lrelu(float x){ return x >= 0.0f ? x : 0.2f*x; }
__device__ __forceinline__ float ldx(const u16t* p){ return b2f(*p); }
__device__ __forceinline__ float ldx(const float* p){ return *p; }

// ---- stats f32 offsets: per-channel [sum,sumsq] pairs ----
#define ST_WG  0
#define ST_WX  128
#define ST_PSI 256
#define ST_BN1 272
#define ST_BN2 784

// ---- bf16 weight element offsets inside WB region ----
#define WOFF_C1 0
#define WOFF_C2 98304
#define WOFF_WG 131072
#define WOFF_WX 147456
#define WTOTAL  155648

// ---- ws byte offsets (time-disjoint aliasing; total ~84.6 MB) ----
#define O_STATS  0u
#define O_WB     8192u
#define O_PSIPRE 319488u
#define O_P2T    581632u        // 4 MB bf16 [B][S][256]
#define O_P1T    4775936u       // 16.7 MB bf16 [B][N][128]; psi-scaled IN PLACE
#define O_INT    21553152u      // 33.5 MB bf16 [B][N][256] interp; h2t aliases later
#define O_H1     55107584u      // 33.5 MB bf16 [B][N][256] h1; bnrelu IN PLACE
// knn scratch lives inside the (not-yet-written) H1 region:
#define O_PD     O_H1                    // 6.29 MB f32 partial dists [B][N][NCH][3]
#define O_PI     (O_H1 + 6291456u)       // 6.29 MB i32 partial idx
#define O_IDX3   (O_H1 + 12582912u)      // 786 KB
#define O_W3     (O_H1 + 13369344u)      // 786 KB (all dead before ygt written)
#define O_YG     O_H1                    // ygt/yxt live steps 5-8, dead before h1 written
#define O_YX     (O_H1 + 8388608u)
#define O_H2     O_INT                   // h2 bf16, written after interp dead
// end = 55107584 + 33554432 = 88662016 B

// ---- 3-NN part 1: per-chunk top-3 over SCH s-points (full occupancy) ----
__global__ __launch_bounds__(256) void knn_part_kernel(const float* __restrict__ xyz1, const float* __restrict__ xyz2,
                                                       float* __restrict__ pd, int* __restrict__ pi){
  __shared__ float4 sp[SCH];
  const int b = blockIdx.z;
  const int c = blockIdx.y;
  const int t = threadIdx.x;
  {
    int s = c*SCH + t;
    float x = xyz2[(b*3+0)*SPTS+s];
    float y = xyz2[(b*3+1)*SPTS+s];
    float z = xyz2[(b*3+2)*SPTS+s];
    sp[t] = make_float4(x, y, z, x*x+y*y+z*z);
  }
  __syncthreads();
  const int n = blockIdx.x*256 + t;
  float px = xyz1[(b*3+0)*NPTS+n];
  float py = xyz1[(b*3+1)*NPTS+n];
  float pz = xyz1[(b*3+2)*NPTS+n];
  float s1 = px*px+py*py+pz*pz;
  float d0=3.4e38f, d1=3.4e38f, d2=3.4e38f;
  int   i0=0, i1=0, i2=0;
  for (int s=0; s<SCH; ++s){
    float4 q = sp[s];
    float dot = fmaf(pz, q.z, fmaf(py, q.y, px*q.x));
    float key = (s1 + q.w) - 2.0f*dot;   // same arithmetic as passing round-4 scan
    if (key < d2){
      int gi = c*SCH + s;
      if (key < d1){
        if (key < d0){ d2=d1; i2=i1; d1=d0; i1=i0; d0=key; i0=gi; }
        else         { d2=d1; i2=i1; d1=key; i1=gi; }
      } else         { d2=key; i2=gi; }
    }
  }
  size_t base = (((size_t)b*NPTS + n)*NCH + c)*3;
  pd[base]=d0; pd[base+1]=d1; pd[base+2]=d2;
  pi[base]=i0; pi[base+1]=i1; pi[base+2]=i2;
}

// ---- 3-NN part 2: merge NCH partial top-3 lists (chunk-order => stable ties) ----
__global__ __launch_bounds__(256) void knn_merge_kernel(const float* __restrict__ pd, const int* __restrict__ pi,
                                                        int* __restrict__ idx3, float* __restrict__ w3){
  const int p = blockIdx.x*256 + threadIdx.x;   // [0, B*N)
  const float* dp = pd + (size_t)p*NCH*3;
  const int*   ip = pi + (size_t)p*NCH*3;
  float d0=3.4e38f, d1=3.4e38f, d2=3.4e38f;
  int   i0=0, i1=0, i2=0;
  #pragma unroll
  for (int k=0; k<NCH*3; ++k){
    float key = dp[k]; int gi = ip[k];
    if (key < d2){
      if (key < d1){
        if (key < d0){ d2=d1; i2=i1; d1=d0; i1=i0; d0=key; i0=gi; }
        else         { d2=d1; i2=i1; d1=key; i1=gi; }
      } else         { d2=key; i2=gi; }
    }
  }
  float r0=1.0f/(d0+1e-8f), r1=1.0f/(d1+1e-8f), r2=1.0f/(d2+1e-8f);
  float rs = r0+r1+r2;
  size_t base = (size_t)p*3;
  idx3[base]=i0; idx3[base+1]=i1; idx3[base+2]=i2;
  w3[base]=r0/rs; w3[base+1]=r1/rs; w3[base+2]=r2/rs;
}

// ---- tiled transpose: src f32 [B][C][NN] -> dst bf16 [B][NN][C] ----
template<int C, int NN>
__global__ __launch_bounds__(256) void tpose_kernel(const float* __restrict__ src, u16t* __restrict__ dst){
  __shared__ float tile[64][65];
  const int n0 = blockIdx.x * 64;
  const int c0 = blockIdx.y * 64;
  const int b  = blockIdx.z;
  const int t  = threadIdx.x;
  #pragma unroll
  for (int i = 0; i < 16; ++i){
    int idx = t + i*256;
    int cc = idx >> 6, nn = idx & 63;
    tile[cc][nn] = src[((size_t)b*C + c0 + cc)*NN + n0 + nn];
  }
  __syncthreads();
  #pragma unroll
  for (int i = 0; i < 16; ++i){
    int idx = t + i*256;
    int nn = idx >> 6, cc = idx & 63;
    dst[((size_t)b*NN + n0 + nn)*C + c0 + cc] = f2b(tile[cc][nn]);
  }
}

// ---- weight convert f32 -> bf16 into WB ----
__global__ __launch_bounds__(256) void wcvt_kernel(const float* __restrict__ w1, const float* __restrict__ w2,
                                                   const float* __restrict__ wg, const float* __restrict__ wx,
                                                   u16t* __restrict__ wb){
  int i = blockIdx.x*256 + threadIdx.x;
  if (i >= WTOTAL) return;
  float v;
  if      (i < WOFF_C2) v = w1[i];
  else if (i < WOFF_WG) v = w2[i - WOFF_C2];
  else if (i < WOFF_WX) v = wg[i - WOFF_WG];
  else                  v = wx[i - WOFF_WX];
  wb[i] = f2b(v);
}

// ---- interp: point-major out [B][N][256] ----
__global__ __launch_bounds__(256) void interp_kernel(const u16t* __restrict__ p2t, const int* __restrict__ idx3,
                                                     const float* __restrict__ w3, u16t* __restrict__ it){
  const int bid = blockIdx.x;
  const int b = bid >> 8;
  const int n0 = (bid & 255) * 64;
  const int wv = threadIdx.x >> 6;
  const int lane = threadIdx.x & 63;
  const int n = n0 + lane;
  size_t pb = ((size_t)b*NPTS + n)*3;
  int i0 = idx3[pb], i1 = idx3[pb+1], i2 = idx3[pb+2];
  float w0 = w3[pb], w1 = w3[pb+1], w2 = w3[pb+2];
  const u16t* r0 = p2t + ((size_t)b*SPTS + i0)*256;
  const u16t* r1 = p2t + ((size_t)b*SPTS + i1)*256;
  const u16t* r2 = p2t + ((size_t)b*SPTS + i2)*256;
  u16t* orow = it + ((size_t)b*NPTS + n)*256;
  for (int c = wv*64; c < wv*64 + 64; c += 8){
    uint4 q0 = *reinterpret_cast<const uint4*>(r0 + c);
    uint4 q1 = *reinterpret_cast<const uint4*>(r1 + c);
    uint4 q2 = *reinterpret_cast<const uint4*>(r2 + c);
    const u32t* a0 = reinterpret_cast<const u32t*>(&q0);
    const u32t* a1 = reinterpret_cast<const u32t*>(&q1);
    const u32t* a2 = reinterpret_cast<const u32t*>(&q2);
    u32t ow[4];
    #pragma unroll
    for (int j = 0; j < 4; ++j){
      u32t u0 = a0[j], u1 = a1[j], u2 = a2[j];
      float lo = fmaf(w2, b2f((u16t)u2), fmaf(w1, b2f((u16t)u1), w0*b2f((u16t)u0)));
      float hi = fmaf(w2, b2f((u16t)(u2>>16)), fmaf(w1, b2f((u16t)(u1>>16)), w0*b2f((u16t)(u0>>16))));
      ow[j] = (u32t)f2b(lo) | ((u32t)f2b(hi) << 16);
    }
    *reinterpret_cast<uint4*>(orow + c) = make_uint4(ow[0], ow[1], ow[2], ow[3]);
  }
}

// ---- MFMA conv1x1: y[B][N][OUT] = W[OUT][CIN] . x[B][N][CIN] + bias (raw, pre-BN) ----
template<int CIN, int OUT, bool SPLIT>
__global__ __launch_bounds__(256, 1) void mfma_conv_kernel(const u16t* __restrict__ xa, const u16t* __restrict__ xb,
                                                           const u16t* __restrict__ W, const float* __restrict__ bias,
                                                           u16t* __restrict__ y){
  constexpr int MW = OUT/4;      // per-wave M slice
  constexpr int MF = MW/16;      // m-fragments per wave
  constexpr int KS = CIN/32;     // k-steps
  const int bid = blockIdx.x;
  const int b = bid >> 8;
  const int n0 = (bid & 255) * 64;
  const int wv = threadIdx.x >> 6;
  const int lane = threadIdx.x & 63;
  const int lr = lane & 15;
  const int kg = lane >> 4;
  const int m0 = wv * MW;

  f32x4 acc[MF][4];
  #pragma unroll
  for (int mf = 0; mf < MF; ++mf)
    #pragma unroll
    for (int nf = 0; nf < 4; ++nf){ acc[mf][nf][0]=0.f; acc[mf][nf][1]=0.f; acc[mf][nf][2]=0.f; acc[mf][nf][3]=0.f; }

  const u16t* bA[4]; const u16t* bB[4];
  #pragma unroll
  for (int nf = 0; nf < 4; ++nf){
    int n = n0 + nf*16 + lr;
    if (SPLIT){
      bA[nf] = xa + ((size_t)b*NPTS + n)*128 + kg*8;
      bB[nf] = xb + ((size_t)b*NPTS + n)*256 + kg*8;
    } else {
      bA[nf] = xa + ((size_t)b*NPTS + n)*CIN + kg*8;
    }
  }

  #pragma unroll
  for (int k0 = 0; k0 < KS; ++k0){
    s16x8 av[MF];
    #pragma unroll
    for (int mf = 0; mf < MF; ++mf)
      av[mf] = *reinterpret_cast<const s16x8*>(W + (size_t)(m0 + mf*16 + lr)*CIN + k0*32 + kg*8);
    s16x8 bv[4];
    #pragma unroll
    for (int nf = 0; nf < 4; ++nf){
      const u16t* p;
      if (SPLIT) p = (k0 < 4) ? (bA[nf] + k0*32) : (bB[nf] + (k0-4)*32);
      else       p = bA[nf] + k0*32;
      bv[nf] = *reinterpret_cast<const s16x8*>(p);
    }
    #pragma unroll
    for (int mf = 0; mf < MF; ++mf)
      #pragma unroll
      for (int nf = 0; nf < 4; ++nf)
        acc[mf][nf] = __builtin_amdgcn_mfma_f32_16x16x32_bf16(av[mf], bv[nf], acc[mf][nf], 0, 0, 0);
  }

  #pragma unroll
  for (int mf = 0; mf < MF; ++mf){
    int mb = m0 + mf*16 + kg*4;
    float4 bs = *reinterpret_cast<const float4*>(bias + mb);
    #pragma unroll
    for (int nf = 0; nf < 4; ++nf){
      int n = n0 + nf*16 + lr;
      float v0 = acc[mf][nf][0] + bs.x;
      float v1 = acc[mf][nf][1] + bs.y;
      float v2 = acc[mf][nf][2] + bs.z;
      float v3 = acc[mf][nf][3] + bs.w;
      uint2 pv;
      pv.x = (u32t)f2b(v0) | ((u32t)f2b(v1) << 16);
      pv.y = (u32t)f2b(v2) | ((u32t)f2b(v3) << 16);
      *reinterpret_cast<uint2*>(y + ((size_t)b*NPTS + n)*OUT + mb) = pv;
    }
  }
}

// ---- batch stats: sum/sumsq per channel over all B*N points; x is [P][C] ----
template<int C, typename T>
__global__ __launch_bounds__(256) void stats_kernel(const T* __restrict__ x, float* __restrict__ st){
  constexpr int G = 256 / C;
  const int t = threadIdx.x;
  const int c = t & (C - 1);
  const int g = t / C;
  const int p0 = blockIdx.x * 256;
  float s = 0.f, q = 0.f;
  for (int i = g; i < 256; i += G){
    float v = ldx(x + (size_t)(p0 + i)*C + c);
    s += v; q += v*v;
  }
  if (G > 1){
    __shared__ float ls[256], lq[256];
    ls[t] = s; lq[t] = q;
    __syncthreads();
    if (t < C){
      #pragma unroll
      for (int gg = 1; gg < G; ++gg){ s += ls[t + gg*C]; q += lq[t + gg*C]; }
      atomicAdd(&st[c*2], s); atomicAdd(&st[c*2+1], q);
    }
  } else {
    atomicAdd(&st[c*2], s); atomicAdd(&st[c*2+1], q);
  }
}

// ---- gate: psi_pre[p] = psi_w . lrelu(bn(yg)+bn(yx)) + psi_b, + psi stats ----
__global__ __launch_bounds__(256) void gate_kernel(const u16t* __restrict__ yg, const u16t* __restrict__ yx,
                                                   const float* __restrict__ stg, const float* __restrict__ stx,
                                                   const float* __restrict__ wg_bn_g, const float* __restrict__ wg_bn_b,
                                                   const float* __restrict__ wx_bn_g, const float* __restrict__ wx_bn_b,
                                                   const float* __restrict__ psi_w, const float* __restrict__ psi_b,
                                                   float* __restrict__ psipre, float* __restrict__ stpsi){
  __shared__ float lag[64], lbg[64], lax[64], lbx[64], lpw[64];
  __shared__ float red[8];
  const int t = threadIdx.x;
  if (t < 64){
    float m  = stg[t*2] * (1.0f/CNTF);
    float vv = fmaxf(stg[t*2+1]*(1.0f/CNTF) - m*m, 0.0f);
    float iv = 1.0f/sqrtf(vv + BNEPS);
    float gm = wg_bn_g[t];
    lag[t] = gm*iv; lbg[t] = wg_bn_b[t] - m*gm*iv;
    m  = stx[t*2] * (1.0f/CNTF);
    vv = fmaxf(stx[t*2+1]*(1.0f/CNTF) - m*m, 0.0f);
    iv = 1.0f/sqrtf(vv + BNEPS);
    gm = wx_bn_g[t];
    lax[t] = gm*iv; lbx[t] = wx_bn_b[t] - m*gm*iv;
    lpw[t] = psi_w[t];
  }
  __syncthreads();
  const int p = blockIdx.x*256 + t;
  const u16t* rg = yg + (size_t)p*64;
  const u16t* rx = yx + (size_t)p*64;
  float acc = psi_b[0];
  #pragma unroll
  for (int u = 0; u < 8; ++u){
    uint4 qg = *reinterpret_cast<const uint4*>(rg + u*8);
    uint4 qx = *reinterpret_cast<const uint4*>(rx + u*8);
    const u32t* g4 = reinterpret_cast<const u32t*>(&qg);
    const u32t* x4 = reinterpret_cast<const u32t*>(&qx);
    #pragma unroll
    for (int e = 0; e < 4; ++e){
      int j = u*8 + e*2;
      float gv0 = fmaf(b2f((u16t)g4[e]),        lag[j],   lbg[j]);
      float xv0 = fmaf(b2f((u16t)x4[e]),        lax[j],   lbx[j]);
      float gv1 = fmaf(b2f((u16t)(g4[e]>>16)),  lag[j+1], lbg[j+1]);
      float xv1 = fmaf(b2f((u16t)(x4[e]>>16)),  lax[j+1], lbx[j+1]);
      acc = fmaf(lpw[j],   lrelu(gv0 + xv0), acc);
      acc = fmaf(lpw[j+1], lrelu(gv1 + xv1), acc);
    }
  }
  psipre[p] = acc;
  float s = acc, q = acc*acc;
  #pragma unroll
  for (int o = 32; o; o >>= 1){ s += __shfl_xor(s, o); q += __shfl_xor(q, o); }
  if ((t & 63) == 0){ red[(t>>6)*2] = s; red[(t>>6)*2+1] = q; }
  __syncthreads();
  if (t == 0){
    atomicAdd(&stpsi[0], red[0]+red[2]+red[4]+red[6]);
    atomicAdd(&stpsi[1], red[1]+red[3]+red[5]+red[7]);
  }
}

// ---- psi = sigmoid(bn(psi_pre)); scale p1t rows in place ----
__global__ __launch_bounds__(256) void scale_p1_kernel(u16t* __restrict__ p1t, const float* __restrict__ psipre,
                                                       const float* __restrict__ stpsi,
                                                       const float* __restrict__ psi_bn_g, const float* __restrict__ psi_bn_b){
  const int p = blockIdx.x*256 + threadIdx.x;
  float m  = stpsi[0]*(1.0f/CNTF);
  float vv = fmaxf(stpsi[1]*(1.0f/CNTF) - m*m, 0.0f);
  float iv = 1.0f/sqrtf(vv + BNEPS);
  float ap = psi_bn_g[0]*iv;
  float bp = psi_bn_b[0] - m*ap;
  float z  = fmaf(psipre[p], ap, bp);
  float psi = 1.0f/(1.0f + expf(-z));
  u16t* r = p1t + (size_t)p*128;
  #pragma unroll
  for (int u = 0; u < 16; ++u){
    uint4 q = *reinterpret_cast<uint4*>(r + u*8);
    u32t* a = reinterpret_cast<u32t*>(&q);
    #pragma unroll
    for (int j = 0; j < 4; ++j){
      float lo = b2f((u16t)a[j]) * psi;
      float hi = b2f((u16t)(a[j]>>16)) * psi;
      a[j] = (u32t)f2b(lo) | ((u32t)f2b(hi) << 16);
    }
    *reinterpret_cast<uint4*>(r + u*8) = q;
  }
}

// ---- bn1 + lrelu in place on h1 [P][256] bf16 ----
__global__ __launch_bounds__(256) void bnrelu256_kernel(u16t* __restrict__ x, const float* __restrict__ st,
                                                        const float* __restrict__ g, const float* __restrict__ bb){
  __shared__ float sa[256], sc[256];
  const int t = threadIdx.x;
  {
    float m  = st[t*2]*(1.0f/CNTF);
    float vv = fmaxf(st[t*2+1]*(1.0f/CNTF) - m*m, 0.0f);
    float iv = 1.0f/sqrtf(vv + BNEPS);
    float gm = g[t];
    sa[t] = gm*iv; sc[t] = bb[t] - m*gm*iv;
  }
  __syncthreads();
  size_t e4 = ((size_t)blockIdx.x*256 + t)*4;
  int c0 = (int)(e4 & 255);
  uint2 v = *reinterpret_cast<uint2*>(x + e4);
  float f0 = lrelu(fmaf(b2f((u16t)v.x),        sa[c0],   sc[c0]));
  float f1 = lrelu(fmaf(b2f((u16t)(v.x>>16)),  sa[c0+1], sc[c0+1]));
  float f2 = lrelu(fmaf(b2f((u16t)v.y),        sa[c0+2], sc[c0+2]));
  float f3 = lrelu(fmaf(b2f((u16t)(v.y>>16)),  sa[c0+3], sc[c0+3]));
  v.x = (u32t)f2b(f0) | ((u32t)f2b(f1) << 16);
  v.y = (u32t)f2b(f2) | ((u32t)f2b(f3) << 16);
  *reinterpret_cast<uint2*>(x + e4) = v;
}

// ---- final: out[b][m][n] f32 = lrelu(bn2(h2[b][n][m])) via LDS tile transpose ----
__global__ __launch_bounds__(256) void final_kernel(const u16t* __restrict__ h2, const float* __restrict__ st,
                                                    const float* __restrict__ g, const float* __restrict__ bb,
                                                    float* __restrict__ out){
  __shared__ float am[128], cm[128];
  __shared__ float tile[64][129];
  const int t = threadIdx.x;
  if (t < 128){
    float m  = st[t*2]*(1.0f/CNTF);
    float vv = fmaxf(st[t*2+1]*(1.0f/CNTF) - m*m, 0.0f);
    float iv = 1.0f/sqrtf(vv + BNEPS);
    float gm = g[t];
    am[t] = gm*iv; cm[t] = bb[t] - m*gm*iv;
  }
  __syncthreads();
  const int n0 = blockIdx.x * 64;
  const int b  = blockIdx.y;
  #pragma unroll
  for (int i = 0; i < 32; ++i){
    int idx = t + i*256;
    int mm = idx & 127, nn = idx >> 7;
    float v = fmaf(b2f(h2[((size_t)b*NPTS + n0 + nn)*128 + mm]), am[mm], cm[mm]);
    tile[nn][mm] = lrelu(v);
  }
  __syncthreads();
  #pragma unroll
  for (int i = 0; i < 32; ++i){
    int idx = t + i*256;
    int nn = idx & 63, mm = idx >> 6;
    out[((size_t)(b*128 + mm))*NPTS + n0 + nn] = tile[nn][mm];
  }
}

extern "C" void kernel_launch(void* const* d_in, const int* in_sizes, int n_in,
                              void* d_out, int out_size, void* d_ws, size_t ws_size,
                              hipStream_t stream){
  const float* xyz1    = (const float*)d_in[0];
  const float* xyz2    = (const float*)d_in[1];
  const float* points1 = (const float*)d_in[2];
  const float* points2 = (const float*)d_in[3];
  const float* conv1_w = (const float*)d_in[4];
  const float* conv1_b = (const float*)d_in[5];
  const float* bn1_g   = (const float*)d_in[6];
  const float* bn1_b   = (const float*)d_in[7];
  const float* conv2_w = (const float*)d_in[8];
  const float* conv2_b = (const float*)d_in[9];
  const float* bn2_g   = (const float*)d_in[10];
  const float* bn2_b   = (const float*)d_in[11];
  const float* wg_w    = (const float*)d_in[12];
  const float* wg_b    = (const float*)d_in[13];
  const float* wg_bn_g = (const float*)d_in[14];
  const float* wg_bn_b = (const float*)d_in[15];
  const float* wx_w    = (const float*)d_in[16];
  const float* wx_b    = (const float*)d_in[17];
  const float* wx_bn_g = (const float*)d_in[18];
  const float* wx_bn_b = (const float*)d_in[19];
  const float* psi_w   = (const float*)d_in[20];
  const float* psi_b   = (const float*)d_in[21];
  const float* psi_bn_g= (const float*)d_in[22];
  const float* psi_bn_b= (const float*)d_in[23];

  char* ws = (char*)d_ws;
  float* stats  = (float*)(ws + O_STATS);
  u16t*  wb     = (u16t*)(ws + O_WB);
  float* psipre = (float*)(ws + O_PSIPRE);
  u16t*  p2t    = (u16t*)(ws + O_P2T);
  u16t*  p1t    = (u16t*)(ws + O_P1T);
  u16t*  itp    = (u16t*)(ws + O_INT);
  u16t*  h1t    = (u16t*)(ws + O_H1);
  float* pd     = (float*)(ws + O_PD);
  int*   pi     = (int*)(ws + O_PI);
  int*   idx3   = (int*)(ws + O_IDX3);
  float* w3     = (float*)(ws + O_W3);
  u16t*  ygt    = (u16t*)(ws + O_YG);
  u16t*  yxt    = (u16t*)(ws + O_YX);
  u16t*  h2t    = (u16t*)(ws + O_H2);

  hipMemsetAsync(ws + O_STATS, 0, 8192, stream);

  knn_part_kernel<<<dim3(NPTS/256, NCH, Bq), 256, 0, stream>>>(xyz1, xyz2, pd, pi);
  knn_merge_kernel<<<(Bq*NPTS)/256, 256, 0, stream>>>(pd, pi, idx3, w3);
  tpose_kernel<256, SPTS><<<dim3(SPTS/64, 4, Bq), 256, 0, stream>>>(points2, p2t);
  interp_kernel<<<Bq*(NPTS/64), 256, 0, stream>>>(p2t, idx3, w3, itp);
  tpose_kernel<128, NPTS><<<dim3(NPTS/64, 2, Bq), 256, 0, stream>>>(points1, p1t);
  wcvt_kernel<<<(WTOTAL+255)/256, 256, 0, stream>>>(conv1_w, conv2_w, wg_w, wx_w, wb);

  mfma_conv_kernel<256, 64, false><<<Bq*(NPTS/64), 256, 0, stream>>>(itp, nullptr, wb+WOFF_WG, wg_b, ygt);
  mfma_conv_kernel<128, 64, false><<<Bq*(NPTS/64), 256, 0, stream>>>(p1t, nullptr, wb+WOFF_WX, wx_b, yxt);
  stats_kernel<64, u16t><<<256, 256, 0, stream>>>(ygt, stats+ST_WG);
  stats_kernel<64, u16t><<<256, 256, 0, stream>>>(yxt, stats+ST_WX);
  gate_kernel<<<256, 256, 0, stream>>>(ygt, yxt, stats+ST_WG, stats+ST_WX,
                                       wg_bn_g, wg_bn_b, wx_bn_g, wx_bn_b,
                                       psi_w, psi_b, psipre, stats+ST_PSI);
  scale_p1_kernel<<<256, 256, 0, stream>>>(p1t, psipre, stats+ST_PSI, psi_bn_g, psi_bn_b);

  mfma_conv_kernel<384, 256, true><<<Bq*(NPTS/64), 256, 0, stream>>>(p1t, itp, wb+WOFF_C1, conv1_b, h1t);
  stats_kernel<256, u16t><<<256, 256, 0, stream>>>(h1t, stats+ST_BN1);
  bnrelu256_kernel<<<16384, 256, 0, stream>>>(h1t, stats+ST_BN1, bn1_g, bn1_b);

  mfma_conv_kernel<256, 128, false><<<Bq*(NPTS/64), 256, 0, stream>>>(h1t, nullptr, wb+WOFF_C2, conv2_b, h2t);
  stats_kernel<128, u16t><<<256, 256, 0, stream>>>(h2t, stats+ST_BN2);
  final_kernel<<<dim3(NPTS/64, Bq), 256, 0, stream>>>(h2t, stats+ST_BN2, bn2_g, bn2_b, (float*)d_out);
}